// Round 6
// baseline (206.249 us; speedup 1.0000x reference)
//
#include <hip/hip_runtime.h>
#include <hip/hip_bf16.h>
#include <stdint.h>

typedef __attribute__((ext_vector_type(8))) short bf16x8;
typedef __attribute__((ext_vector_type(4))) float f32x4;

#define S_2LOG2E 2.8853900817779268f   // 2*log2(e): tanh(x)=1-2/(2^(x*S)+1)

#if __has_builtin(__builtin_amdgcn_exp2f)
#define EXP2F(x) __builtin_amdgcn_exp2f(x)
#else
#define EXP2F(x) __expf((x) * 0.6931471805599453f)
#endif
#if __has_builtin(__builtin_amdgcn_rcpf)
#define RCPF(x) __builtin_amdgcn_rcpf(x)
#else
#define RCPF(x) (1.0f / (x))
#endif

__device__ __forceinline__ float tanh_fast(float x) {   // prep only
    float e = __expf(2.0f * x);
    return 1.0f - 2.0f / (e + 1.0f);
}

// ---- bf16 pack via native v_cvt_pk_bf16_f32 (RNE) ----
__device__ __forceinline__ bf16x8 pack2(float4 a, float4 b) {
    union { bf16x8 v; __hip_bfloat162 h[4]; } r;
    r.h[0] = __float22bfloat162_rn(make_float2(a.x, a.y));
    r.h[1] = __float22bfloat162_rn(make_float2(a.z, a.w));
    r.h[2] = __float22bfloat162_rn(make_float2(b.x, b.y));
    r.h[3] = __float22bfloat162_rn(make_float2(b.z, b.w));
    return r.v;
}
__device__ __forceinline__ float4 scl4(float4 a) {      // fold S into W at cast time
    a.x *= S_2LOG2E; a.y *= S_2LOG2E; a.z *= S_2LOG2E; a.w *= S_2LOG2E;
    return a;
}
#define MFMA16(a, b, c) __builtin_amdgcn_mfma_f32_16x16x32_bf16((a), (b), (c), 0, 0, 0)

// =========================================================================
// Kernel 1 (prep): q, scaled biases, scaled W frags, out-zero, bf16 table
// cast (1 chunk/thread). Unchanged.
// =========================================================================
__global__ void finerec_prep(
    const float* __restrict__ user_emb, const float* __restrict__ attr,
    const float* __restrict__ Wq, const float* __restrict__ bq,
    const float* __restrict__ Wk, const float* __restrict__ bk,
    const float* __restrict__ Wv, const float* __restrict__ bv,
    const float* __restrict__ item_table, const float* __restrict__ opin_table,
    float* __restrict__ q_ws, float* __restrict__ bkz_ws, float* __restrict__ bvz_ws,
    short* __restrict__ wf_ws, short* __restrict__ itb, short* __restrict__ opb,
    float* __restrict__ out, int U, int n_item, int n_opi, int qb)
{
    const int bx = blockIdx.x, tid = threadIdx.x;
    if (bx >= qb + 49) {                     // ---- table cast to bf16 chunks ----
        const int castb = gridDim.x - qb - 49;
        const int gid = (bx - qb - 49) * 256 + tid;
        const int stride = castb * 256;
        const int tci = n_item * 16, tc = (n_item + n_opi) * 16;
        for (int c = gid; c < tc; c += stride) {
            if (c < tci) {
                const float* src = item_table + (size_t)c * 8;
                ((bf16x8*)itb)[c] = pack2(*(const float4*)src, *(const float4*)(src + 4));
            } else {
                const float* src = opin_table + (size_t)(c - tci) * 8;
                ((bf16x8*)opb)[c - tci] = pack2(*(const float4*)src, *(const float4*)(src + 4));
            }
        }
        return;
    }
    if (bx >= qb + 9) {                      // ---- zero the atomic output ----
        const int gid = (bx - qb - 9) * 256 + tid;
        float4 z = {0.0f, 0.0f, 0.0f, 0.0f};
        for (int i = gid; i < U * 32; i += 40 * 256) ((float4*)out)[i] = z;
        return;
    }
    if (bx >= qb + 1) {                      // ---- weight cast (pre-scaled by S) ----
        const int bi = bx - qb - 1;
#pragma unroll
        for (int t = 0; t < 2; ++t) {
            const int g = bi * 512 + t * 256 + tid;           // 0..4095
            const int mat = g >> 11, gg = g & 2047, r = gg >> 4, c = gg & 15;
            const float* src = (mat ? Wv : Wk) + r * 128 + c * 8;
            ((bf16x8*)wf_ws)[(mat << 11) + (r << 4) + (c ^ (r & 15))] =
                pack2(scl4(*(const float4*)src), scl4(*(const float4*)(src + 4)));
        }
        return;
    }
    if (bx == qb) {                          // ---- pre-scaled biases ----
        if (tid < 128) {
            const float* wr = Wk + tid * 128;
            float s = bk[tid];
            for (int k = 0; k < 128; k += 4) {
                float4 w4 = *(const float4*)(wr + k);
                float4 a4 = *(const float4*)(attr + k);
                s += w4.x * a4.x + w4.y * a4.y + w4.z * a4.z + w4.w * a4.w;
            }
            bkz_ws[tid] = s * S_2LOG2E;
        } else if (tid < 256) {
            bvz_ws[tid - 128] = bv[tid - 128] * S_2LOG2E;
        }
        return;
    }
    // ---- q: 64 users per block (16 per wave) ----
    const int wv = tid >> 6, lane = tid & 63;
    const int l15 = lane & 15, quad = lane >> 4;
    const int u0 = (bx * 4 + wv) * 16;
    int ur = u0 + l15; if (ur >= U) ur = U - 1;
    const float* up = user_emb + (size_t)ur * 128 + quad * 8;
    bf16x8 af[4];
#pragma unroll
    for (int ks = 0; ks < 4; ++ks)
        af[ks] = pack2(*(const float4*)(up + ks * 32), *(const float4*)(up + ks * 32 + 4));
#pragma unroll
    for (int nt = 0; nt < 8; ++nt) {
        const int n = nt * 16 + l15;
        const float* wp = Wq + n * 128 + quad * 8;
        f32x4 acc = {0, 0, 0, 0};
#pragma unroll
        for (int ks = 0; ks < 4; ++ks) {
            bf16x8 bf = pack2(*(const float4*)(wp + ks * 32), *(const float4*)(wp + ks * 32 + 4));
            acc = MFMA16(af[ks], bf, acc);
        }
        const float bqv = bq[n];
#pragma unroll
        for (int r = 0; r < 4; ++r) {
            int row = u0 + quad * 4 + r;
            if (row < U) q_ws[row * 128 + nt * 16 + l15] = tanh_fast(acc[r] + bqv);
        }
    }
}

// =========================================================================
// Kernel 2 (main): 32-ROW JOBS. Each wave processes 32 (u,l) rows as two
// 16-row halves (lo/hi) sharing ONE W-fragment ds_read stream -> LDS
// traffic per row HALVED (the dominant shared pipe at 44% busy), job count
// halved (serial gather/index latency + shuffles + atomics amortized 2x),
// and the independent lo/hi MFMA chains double per-wave ILP. 512-thread
// blocks, launch_bounds(512,4): VGPR cap 128 (natural ~110, no squeeze),
// 2 blocks/CU x 8 waves = 16 waves/CU, LDS 2x66.5=133 KB. Rolled nt loops
// (round-4 scar: never unroll against a register cap). Jobs span <=2 users
// (32<L=50); either half may straddle -> per-element row<bb select.
// =========================================================================
template<int BF16, int LC>
__global__ __launch_bounds__(512, 4) void finerec_main(
    const float* __restrict__ item_table, const float* __restrict__ opin_table,
    const int* __restrict__ item_seqs, const int* __restrict__ opin_seqs,
    const float* __restrict__ q_ws, const float* __restrict__ bkz_ws,
    const float* __restrict__ bvz_ws, const short* __restrict__ wf_ws,
    const short* __restrict__ itb, const short* __restrict__ opb,
    float* __restrict__ out, int U, int Lrt)
{
    __shared__ __align__(16) short wlds[32768];   // S*Wk + S*Wv frag chunks
    __shared__ float bkz_lds[128], bvz_lds[128];

    const int L = LC ? LC : Lrt;
    const int tid = threadIdx.x;
    const int wv = tid >> 6, lane = tid & 63, l15 = lane & 15, quad = lane >> 4;

    const bf16x8* wsrc = (const bf16x8*)wf_ws;
    bf16x8* wldsv = (bf16x8*)wlds;
#pragma unroll
    for (int i = 0; i < 8; ++i)
        wldsv[i * 512 + tid] = wsrc[i * 512 + tid];
    if (tid < 128)      bkz_lds[tid]       = bkz_ws[tid];
    else if (tid < 256) bvz_lds[tid - 128] = bvz_ws[tid - 128];
    __syncthreads();   // the ONLY block barrier

    const int UL = U * L;
    const int njobs = (UL + 31) >> 5;
    const int nwaves = gridDim.x * 8;

#pragma unroll 1
    for (int job = blockIdx.x * 8 + wv; job < njobs; job += nwaves) {
        const int g0 = job << 5;                 // first flattened row (32/job)
        const int uA = g0 / L;
        const int bb = L - (g0 - uA * L);        // rows of uA in this job, [2,50]
        const bool split = (bb < 32) && (uA + 1 < U);

        int vi = 0, vo = 0;
        if (lane < 32 && g0 + lane < UL) {
            vi = item_seqs[g0 + lane];
            vo = opin_seqs[g0 + lane];
        }
        const unsigned long long mb = __ballot(vi > 0);

        // ---- gather item rows (both halves) -> A-frags ----
        const int idxL = __shfl(vi, l15);
        const int idxH = __shfl(vi, l15 + 16);
        bf16x8 aiL[4], aiH[4];
        if (BF16) {
            const bf16x8* pL = (const bf16x8*)itb + (size_t)idxL * 16 + quad;
            const bf16x8* pH = (const bf16x8*)itb + (size_t)idxH * 16 + quad;
#pragma unroll
            for (int ks = 0; ks < 4; ++ks) { aiL[ks] = pL[ks * 4]; aiH[ks] = pH[ks * 4]; }
        } else {
            const float* pL = item_table + (size_t)idxL * 128 + quad * 8;
            const float* pH = item_table + (size_t)idxH * 128 + quad * 8;
#pragma unroll
            for (int ks = 0; ks < 4; ++ks) {
                aiL[ks] = pack2(*(const float4*)(pL + ks * 32), *(const float4*)(pL + ks * 32 + 4));
                aiH[ks] = pack2(*(const float4*)(pH + ks * 32), *(const float4*)(pH + ks * 32 + 4));
            }
        }

        const float* qpA = q_ws + (size_t)uA * 128;

        // ---- K pass: one wf ds_read feeds BOTH half chains ----
        float waccL[4] = {0, 0, 0, 0}, waccH[4] = {0, 0, 0, 0};
        if (!split) {
            float sq = 0.0f;
#pragma unroll 1
            for (int nt = 0; nt < 8; ++nt) {
                const int n = nt * 16 + l15;
                const float qa = qpA[n];
                const float bz = bkz_lds[n];
                f32x4 cL = {bz, bz, bz, bz}, cH = {bz, bz, bz, bz};
#pragma unroll
                for (int ks = 0; ks < 4; ++ks) {
                    const bf16x8 wf = wldsv[(n << 4) + ((ks * 4 + quad) ^ l15)];
                    cL = MFMA16(aiL[ks], wf, cL);
                    cH = MFMA16(aiH[ks], wf, cH);
                }
                const float m2qa = -2.0f * qa;
                sq += qa;
#pragma unroll
                for (int r = 0; r < 4; ++r) {
                    const float rcL = RCPF(EXP2F(cL[r]) + 1.0f);
                    const float rcH = RCPF(EXP2F(cH[r]) + 1.0f);
                    waccL[r] = fmaf(m2qa, rcL, waccL[r]);
                    waccH[r] = fmaf(m2qa, rcH, waccH[r]);
                }
            }
#pragma unroll
            for (int r = 0; r < 4; ++r) { waccL[r] += sq; waccH[r] += sq; }
        } else {
            float sqA = 0.0f, sqB = 0.0f;
#pragma unroll 1
            for (int nt = 0; nt < 8; ++nt) {
                const int n = nt * 16 + l15;
                const float qa  = qpA[n];
                const float qb2 = qpA[128 + n];
                const float bz = bkz_lds[n];
                f32x4 cL = {bz, bz, bz, bz}, cH = {bz, bz, bz, bz};
#pragma unroll
                for (int ks = 0; ks < 4; ++ks) {
                    const bf16x8 wf = wldsv[(n << 4) + ((ks * 4 + quad) ^ l15)];
                    cL = MFMA16(aiL[ks], wf, cL);
                    cH = MFMA16(aiH[ks], wf, cH);
                }
                const float m2qa = -2.0f * qa, m2qb = -2.0f * qb2;
                sqA += qa; sqB += qb2;
#pragma unroll
                for (int r = 0; r < 4; ++r) {
                    const float rcL = RCPF(EXP2F(cL[r]) + 1.0f);
                    const float rcH = RCPF(EXP2F(cH[r]) + 1.0f);
                    waccL[r] = fmaf((quad * 4 + r      < bb) ? m2qa : m2qb, rcL, waccL[r]);
                    waccH[r] = fmaf((quad * 4 + r + 16 < bb) ? m2qa : m2qb, rcH, waccH[r]);
                }
            }
#pragma unroll
            for (int r = 0; r < 4; ++r) {
                waccL[r] += (quad * 4 + r      < bb) ? sqA : sqB;
                waccH[r] += (quad * 4 + r + 16 < bb) ? sqA : sqB;
            }
        }
        // ---- w: reduce over 16 cols within quad + padding mask ----
        float wL[4], wH[4];
#pragma unroll
        for (int r = 0; r < 4; ++r) {
            float t = waccL[r];
            t += __shfl_xor(t, 1); t += __shfl_xor(t, 2);
            t += __shfl_xor(t, 4); t += __shfl_xor(t, 8);
            wL[r] = ((mb >> (quad * 4 + r)) & 1ull) ? t : 0.0f;
            float u = waccH[r];
            u += __shfl_xor(u, 1); u += __shfl_xor(u, 2);
            u += __shfl_xor(u, 4); u += __shfl_xor(u, 8);
            wH[r] = ((mb >> (16 + quad * 4 + r)) & 1ull) ? u : 0.0f;
        }
        // ---- gather opin rows -> second A-frags (chained MFMA linearity) ----
        const int odL = __shfl(vo, l15);
        const int odH = __shfl(vo, l15 + 16);
        bf16x8 aoL[4], aoH[4];
        if (BF16) {
            const bf16x8* pL = (const bf16x8*)opb + (size_t)odL * 16 + quad;
            const bf16x8* pH = (const bf16x8*)opb + (size_t)odH * 16 + quad;
#pragma unroll
            for (int ks = 0; ks < 4; ++ks) { aoL[ks] = pL[ks * 4]; aoH[ks] = pH[ks * 4]; }
        } else {
            const float* pL = opin_table + (size_t)odL * 128 + quad * 8;
            const float* pH = opin_table + (size_t)odH * 128 + quad * 8;
#pragma unroll
            for (int ks = 0; ks < 4; ++ks) {
                aoL[ks] = pack2(*(const float4*)(pL + ks * 32), *(const float4*)(pL + ks * 32 + 4));
                aoH[ks] = pack2(*(const float4*)(pH + ks * 32), *(const float4*)(pH + ks * 32 + 4));
            }
        }
        // ---- V pass: folded tanh; one wf read feeds 4 MFMAs ----
        float m2wL[4], m2wH[4]; float wsL = 0.0f, wsH = 0.0f;
#pragma unroll
        for (int r = 0; r < 4; ++r) {
            m2wL[r] = -2.0f * wL[r]; wsL += wL[r];
            m2wH[r] = -2.0f * wH[r]; wsH += wH[r];
        }
        float* outbase = out + (size_t)uA * 128 + quad * 32 + l15;
        if (!split) {
            float s0 = 0.0f, s1 = 0.0f;
#pragma unroll 1
            for (int nt = 0; nt < 8; ++nt) {
                const int n = nt * 16 + l15;
                const float bz = bvz_lds[n];
                f32x4 cL = {bz, bz, bz, bz}, cH = {bz, bz, bz, bz};
#pragma unroll
                for (int ks = 0; ks < 4; ++ks) {
                    const bf16x8 wf = wldsv[2048 + (n << 4) + ((ks * 4 + quad) ^ l15)];
                    cL = MFMA16(aiL[ks], wf, cL);
                    cL = MFMA16(aoL[ks], wf, cL);
                    cH = MFMA16(aiH[ks], wf, cH);
                    cH = MFMA16(aoH[ks], wf, cH);
                }
                float accL = wsL, accH = wsH;
#pragma unroll
                for (int r = 0; r < 4; ++r) {
                    const float rcL = RCPF(EXP2F(cL[r]) + 1.0f);
                    const float rcH = RCPF(EXP2F(cH[r]) + 1.0f);
                    accL = fmaf(m2wL[r], rcL, accL);
                    accH = fmaf(m2wH[r], rcH, accH);
                }
                float acc = accL + accH;
                acc += __shfl_xor(acc, 16);
                acc += __shfl_xor(acc, 32);
                const bool mine = (quad == (nt >> 1));
                s0 += (mine && !(nt & 1)) ? acc : 0.0f;
                s1 += (mine &&  (nt & 1)) ? acc : 0.0f;
            }
            atomicAdd(outbase, s0);
            atomicAdd(outbase + 16, s1);
        } else {
            float m2wAL[4], m2wAH[4]; float wsAL = 0.0f, wsAH = 0.0f;
#pragma unroll
            for (int r = 0; r < 4; ++r) {
                const bool sL = (quad * 4 + r)      < bb;
                const bool sH = (quad * 4 + r + 16) < bb;
                m2wAL[r] = sL ? m2wL[r] : 0.0f; wsAL += sL ? wL[r] : 0.0f;
                m2wAH[r] = sH ? m2wH[r] : 0.0f; wsAH += sH ? wH[r] : 0.0f;
            }
            float sA0 = 0.0f, sA1 = 0.0f, sB0 = 0.0f, sB1 = 0.0f;
#pragma unroll 1
            for (int nt = 0; nt < 8; ++nt) {
                const int n = nt * 16 + l15;
                const float bz = bvz_lds[n];
                f32x4 cL = {bz, bz, bz, bz}, cH = {bz, bz, bz, bz};
#pragma unroll
                for (int ks = 0; ks < 4; ++ks) {
                    const bf16x8 wf = wldsv[2048 + (n << 4) + ((ks * 4 + quad) ^ l15)];
                    cL = MFMA16(aiL[ks], wf, cL);
                    cL = MFMA16(aoL[ks], wf, cL);
                    cH = MFMA16(aiH[ks], wf, cH);
                    cH = MFMA16(aoH[ks], wf, cH);
                }
                float accTL = wsL, accTH = wsH, accAL = wsAL, accAH = wsAH;
#pragma unroll
                for (int r = 0; r < 4; ++r) {
                    const float rcL = RCPF(EXP2F(cL[r]) + 1.0f);
                    const float rcH = RCPF(EXP2F(cH[r]) + 1.0f);
                    accTL = fmaf(m2wL[r],  rcL, accTL);
                    accAL = fmaf(m2wAL[r], rcL, accAL);
                    accTH = fmaf(m2wH[r],  rcH, accTH);
                    accAH = fmaf(m2wAH[r], rcH, accAH);
                }
                float accT = accTL + accTH;
                float accA = accAL + accAH;
                accT += __shfl_xor(accT, 16); accT += __shfl_xor(accT, 32);
                accA += __shfl_xor(accA, 16); accA += __shfl_xor(accA, 32);
                const float accB = accT - accA;
                const bool mine = (quad == (nt >> 1));
                const bool lo = !(nt & 1);
                sA0 += (mine && lo)  ? accA : 0.0f;
                sA1 += (mine && !lo) ? accA : 0.0f;
                sB0 += (mine && lo)  ? accB : 0.0f;
                sB1 += (mine && !lo) ? accB : 0.0f;
            }
            atomicAdd(outbase, sA0);
            atomicAdd(outbase + 16, sA1);
            atomicAdd(outbase + 128, sB0);        // user uA+1
            atomicAdd(outbase + 144, sB1);
        }
    }
}

extern "C" void kernel_launch(void* const* d_in, const int* in_sizes, int n_in,
                              void* d_out, int out_size, void* d_ws, size_t ws_size,
                              hipStream_t stream) {
    const float* item_table = (const float*)d_in[0];
    const float* opin_table = (const float*)d_in[1];
    const float* user_emb   = (const float*)d_in[2];
    const float* attr       = (const float*)d_in[3];
    const float* Wq = (const float*)d_in[4];
    const float* bq = (const float*)d_in[5];
    const float* Wk = (const float*)d_in[6];
    const float* bk = (const float*)d_in[7];
    const float* Wv = (const float*)d_in[8];
    const float* bv = (const float*)d_in[9];
    const int* item_seqs = (const int*)d_in[10];
    const int* opin_seqs = (const int*)d_in[11];
    float* out = (float*)d_out;

    const int U = in_sizes[2] / 128;        // 10000
    const int L = in_sizes[10] / U;         // 50
    const int n_item = in_sizes[0] / 128;   // 50000
    const int n_opi  = in_sizes[1] / 128;   // 5000

    // ---- ws layout ----
    char* w = (char*)d_ws;
    float* q_ws   = (float*)w;               w += (size_t)U * 128 * 4;
    float* bkz_ws = (float*)w;               w += 512;
    float* bvz_ws = (float*)w;               w += 512;
    short* wf_ws  = (short*)w;               w += 4096 * 16;
    short* itb    = (short*)w;               w += (size_t)n_item * 128 * 2;
    short* opb    = (short*)w;               w += (size_t)n_opi * 128 * 2;
    const size_t need = (size_t)(w - (char*)d_ws);
    const int use_bf16 = (ws_size >= need) ? 1 : 0;

    const int qb = (U + 63) / 64;
    const int castb = use_bf16 ? (((n_item + n_opi) * 16 + 255) / 256) : 0;
    const int prep_grid = qb + 49 + castb;
    finerec_prep<<<prep_grid, 256, 0, stream>>>(
        user_emb, attr, Wq, bq, Wk, bk, Wv, bv, item_table, opin_table,
        q_ws, bkz_ws, bvz_ws, wf_ws, itb, opb, out, U, n_item, n_opi, qb);

    // 512 blocks x 512 threads: exactly 2 blocks/CU co-resident (LDS-capped),
    // grid-stride over 32-row jobs.
    if (use_bf16) {
        if (L == 50)
            finerec_main<1, 50><<<512, 512, 0, stream>>>(
                item_table, opin_table, item_seqs, opin_seqs,
                q_ws, bkz_ws, bvz_ws, wf_ws, itb, opb, out, U, L);
        else
            finerec_main<1, 0><<<512, 512, 0, stream>>>(
                item_table, opin_table, item_seqs, opin_seqs,
                q_ws, bkz_ws, bvz_ws, wf_ws, itb, opb, out, U, L);
    } else {
        if (L == 50)
            finerec_main<0, 50><<<512, 512, 0, stream>>>(
                item_table, opin_table, item_seqs, opin_seqs,
                q_ws, bkz_ws, bvz_ws, wf_ws, itb, opb, out, U, L);
        else
            finerec_main<0, 0><<<512, 512, 0, stream>>>(
                item_table, opin_table, item_seqs, opin_seqs,
                q_ws, bkz_ws, bvz_ws, wf_ws, itb, opb, out, U, L);
    }
}

// Round 7
// 186.431 us; speedup vs baseline: 1.1063x; 1.1063x over previous
//
#include <hip/hip_runtime.h>
#include <hip/hip_bf16.h>
#include <stdint.h>

typedef __attribute__((ext_vector_type(8))) short bf16x8;
typedef __attribute__((ext_vector_type(4))) float f32x4;

#define S_2LOG2E 2.8853900817779268f   // 2*log2(e): tanh(x)=1-2/(2^(x*S)+1)

#if __has_builtin(__builtin_amdgcn_exp2f)
#define EXP2F(x) __builtin_amdgcn_exp2f(x)
#else
#define EXP2F(x) __expf((x) * 0.6931471805599453f)
#endif
#if __has_builtin(__builtin_amdgcn_rcpf)
#define RCPF(x) __builtin_amdgcn_rcpf(x)
#else
#define RCPF(x) (1.0f / (x))
#endif

__device__ __forceinline__ float tanh_fast(float x) {   // prep only
    float e = __expf(2.0f * x);
    return 1.0f - 2.0f / (e + 1.0f);
}

// ---- bf16 pack via native v_cvt_pk_bf16_f32 (RNE) ----
__device__ __forceinline__ bf16x8 pack2(float4 a, float4 b) {
    union { bf16x8 v; __hip_bfloat162 h[4]; } r;
    r.h[0] = __float22bfloat162_rn(make_float2(a.x, a.y));
    r.h[1] = __float22bfloat162_rn(make_float2(a.z, a.w));
    r.h[2] = __float22bfloat162_rn(make_float2(b.x, b.y));
    r.h[3] = __float22bfloat162_rn(make_float2(b.z, b.w));
    return r.v;
}
__device__ __forceinline__ float4 scl4(float4 a) {      // fold S into W at cast time
    a.x *= S_2LOG2E; a.y *= S_2LOG2E; a.z *= S_2LOG2E; a.w *= S_2LOG2E;
    return a;
}
#define MFMA16(a, b, c) __builtin_amdgcn_mfma_f32_16x16x32_bf16((a), (b), (c), 0, 0, 0)

// =========================================================================
// Kernel 1 (prep): q, scaled biases, scaled W frags, out-zero, bf16 table
// cast (1 chunk/thread). Unchanged.
// =========================================================================
__global__ void finerec_prep(
    const float* __restrict__ user_emb, const float* __restrict__ attr,
    const float* __restrict__ Wq, const float* __restrict__ bq,
    const float* __restrict__ Wk, const float* __restrict__ bk,
    const float* __restrict__ Wv, const float* __restrict__ bv,
    const float* __restrict__ item_table, const float* __restrict__ opin_table,
    float* __restrict__ q_ws, float* __restrict__ bkz_ws, float* __restrict__ bvz_ws,
    short* __restrict__ wf_ws, short* __restrict__ itb, short* __restrict__ opb,
    float* __restrict__ out, int U, int n_item, int n_opi, int qb)
{
    const int bx = blockIdx.x, tid = threadIdx.x;
    if (bx >= qb + 49) {                     // ---- table cast to bf16 chunks ----
        const int castb = gridDim.x - qb - 49;
        const int gid = (bx - qb - 49) * 256 + tid;
        const int stride = castb * 256;
        const int tci = n_item * 16, tc = (n_item + n_opi) * 16;
        for (int c = gid; c < tc; c += stride) {
            if (c < tci) {
                const float* src = item_table + (size_t)c * 8;
                ((bf16x8*)itb)[c] = pack2(*(const float4*)src, *(const float4*)(src + 4));
            } else {
                const float* src = opin_table + (size_t)(c - tci) * 8;
                ((bf16x8*)opb)[c - tci] = pack2(*(const float4*)src, *(const float4*)(src + 4));
            }
        }
        return;
    }
    if (bx >= qb + 9) {                      // ---- zero the atomic output ----
        const int gid = (bx - qb - 9) * 256 + tid;
        float4 z = {0.0f, 0.0f, 0.0f, 0.0f};
        for (int i = gid; i < U * 32; i += 40 * 256) ((float4*)out)[i] = z;
        return;
    }
    if (bx >= qb + 1) {                      // ---- weight cast (pre-scaled by S) ----
        const int bi = bx - qb - 1;
#pragma unroll
        for (int t = 0; t < 2; ++t) {
            const int g = bi * 512 + t * 256 + tid;           // 0..4095
            const int mat = g >> 11, gg = g & 2047, r = gg >> 4, c = gg & 15;
            const float* src = (mat ? Wv : Wk) + r * 128 + c * 8;
            ((bf16x8*)wf_ws)[(mat << 11) + (r << 4) + (c ^ (r & 15))] =
                pack2(scl4(*(const float4*)src), scl4(*(const float4*)(src + 4)));
        }
        return;
    }
    if (bx == qb) {                          // ---- pre-scaled biases ----
        if (tid < 128) {
            const float* wr = Wk + tid * 128;
            float s = bk[tid];
            for (int k = 0; k < 128; k += 4) {
                float4 w4 = *(const float4*)(wr + k);
                float4 a4 = *(const float4*)(attr + k);
                s += w4.x * a4.x + w4.y * a4.y + w4.z * a4.z + w4.w * a4.w;
            }
            bkz_ws[tid] = s * S_2LOG2E;
        } else if (tid < 256) {
            bvz_ws[tid - 128] = bv[tid - 128] * S_2LOG2E;
        }
        return;
    }
    // ---- q: 64 users per block (16 per wave) ----
    const int wv = tid >> 6, lane = tid & 63;
    const int l15 = lane & 15, quad = lane >> 4;
    const int u0 = (bx * 4 + wv) * 16;
    int ur = u0 + l15; if (ur >= U) ur = U - 1;
    const float* up = user_emb + (size_t)ur * 128 + quad * 8;
    bf16x8 af[4];
#pragma unroll
    for (int ks = 0; ks < 4; ++ks)
        af[ks] = pack2(*(const float4*)(up + ks * 32), *(const float4*)(up + ks * 32 + 4));
#pragma unroll
    for (int nt = 0; nt < 8; ++nt) {
        const int n = nt * 16 + l15;
        const float* wp = Wq + n * 128 + quad * 8;
        f32x4 acc = {0, 0, 0, 0};
#pragma unroll
        for (int ks = 0; ks < 4; ++ks) {
            bf16x8 bf = pack2(*(const float4*)(wp + ks * 32), *(const float4*)(wp + ks * 32 + 4));
            acc = MFMA16(af[ks], bf, acc);
        }
        const float bqv = bq[n];
#pragma unroll
        for (int r = 0; r < 4; ++r) {
            int row = u0 + quad * 4 + r;
            if (row < U) q_ws[row * 128 + nt * 16 + l15] = tanh_fast(acc[r] + bqv);
        }
    }
}

// =========================================================================
// Kernel 2 (main): 32-ROW JOBS, round-6 structure with the spill fixed.
// Round 6's __launch_bounds__(512,4) acted as MIN 4 BLOCKS/CU -> 64-VGPR
// cap -> scratch spill (VGPR=64, FETCH 65->158MB, WRITE 20->53MB). Now
// __launch_bounds__(512) with NO occupancy floor: natural ~110 VGPR, no
// spill. Occupancy: VGPR<=128 -> 4 waves/SIMD; LDS 66.5KB -> 2 blocks/CU
// -> 16 waves/CU. Each wave: two 16-row halves share ONE W-frag ds_read
// stream (DS per row halved — the dominant shared pipe), job count halved
// (gather/shuffle/atomic latency amortized 2x), lo/hi chains give 2x ILP.
// =========================================================================
template<int BF16, int LC>
__global__ __launch_bounds__(512) void finerec_main(
    const float* __restrict__ item_table, const float* __restrict__ opin_table,
    const int* __restrict__ item_seqs, const int* __restrict__ opin_seqs,
    const float* __restrict__ q_ws, const float* __restrict__ bkz_ws,
    const float* __restrict__ bvz_ws, const short* __restrict__ wf_ws,
    const short* __restrict__ itb, const short* __restrict__ opb,
    float* __restrict__ out, int U, int Lrt)
{
    __shared__ __align__(16) short wlds[32768];   // S*Wk + S*Wv frag chunks
    __shared__ float bkz_lds[128], bvz_lds[128];

    const int L = LC ? LC : Lrt;
    const int tid = threadIdx.x;
    const int wv = tid >> 6, lane = tid & 63, l15 = lane & 15, quad = lane >> 4;

    const bf16x8* wsrc = (const bf16x8*)wf_ws;
    bf16x8* wldsv = (bf16x8*)wlds;
#pragma unroll
    for (int i = 0; i < 8; ++i)
        wldsv[i * 512 + tid] = wsrc[i * 512 + tid];
    if (tid < 128)      bkz_lds[tid]       = bkz_ws[tid];
    else if (tid < 256) bvz_lds[tid - 128] = bvz_ws[tid - 128];
    __syncthreads();   // the ONLY block barrier

    const int UL = U * L;
    const int njobs = (UL + 31) >> 5;
    const int nwaves = gridDim.x * 8;

#pragma unroll 1
    for (int job = blockIdx.x * 8 + wv; job < njobs; job += nwaves) {
        const int g0 = job << 5;                 // first flattened row (32/job)
        const int uA = g0 / L;
        const int bb = L - (g0 - uA * L);        // rows of uA in this job, [2,50]
        const bool split = (bb < 32) && (uA + 1 < U);

        int vi = 0, vo = 0;
        if (lane < 32 && g0 + lane < UL) {
            vi = item_seqs[g0 + lane];
            vo = opin_seqs[g0 + lane];
        }
        const unsigned long long mb = __ballot(vi > 0);

        // ---- gather item rows (both halves) -> A-frags ----
        const int idxL = __shfl(vi, l15);
        const int idxH = __shfl(vi, l15 + 16);
        bf16x8 aiL[4], aiH[4];
        if (BF16) {
            const bf16x8* pL = (const bf16x8*)itb + (size_t)idxL * 16 + quad;
            const bf16x8* pH = (const bf16x8*)itb + (size_t)idxH * 16 + quad;
#pragma unroll
            for (int ks = 0; ks < 4; ++ks) { aiL[ks] = pL[ks * 4]; aiH[ks] = pH[ks * 4]; }
        } else {
            const float* pL = item_table + (size_t)idxL * 128 + quad * 8;
            const float* pH = item_table + (size_t)idxH * 128 + quad * 8;
#pragma unroll
            for (int ks = 0; ks < 4; ++ks) {
                aiL[ks] = pack2(*(const float4*)(pL + ks * 32), *(const float4*)(pL + ks * 32 + 4));
                aiH[ks] = pack2(*(const float4*)(pH + ks * 32), *(const float4*)(pH + ks * 32 + 4));
            }
        }

        const float* qpA = q_ws + (size_t)uA * 128;

        // ---- K pass: one wf ds_read feeds BOTH half chains ----
        float waccL[4] = {0, 0, 0, 0}, waccH[4] = {0, 0, 0, 0};
        if (!split) {
            float sq = 0.0f;
#pragma unroll 1
            for (int nt = 0; nt < 8; ++nt) {
                const int n = nt * 16 + l15;
                const float qa = qpA[n];
                const float bz = bkz_lds[n];
                f32x4 cL = {bz, bz, bz, bz}, cH = {bz, bz, bz, bz};
#pragma unroll
                for (int ks = 0; ks < 4; ++ks) {
                    const bf16x8 wf = wldsv[(n << 4) + ((ks * 4 + quad) ^ l15)];
                    cL = MFMA16(aiL[ks], wf, cL);
                    cH = MFMA16(aiH[ks], wf, cH);
                }
                const float m2qa = -2.0f * qa;
                sq += qa;
#pragma unroll
                for (int r = 0; r < 4; ++r) {
                    const float rcL = RCPF(EXP2F(cL[r]) + 1.0f);
                    const float rcH = RCPF(EXP2F(cH[r]) + 1.0f);
                    waccL[r] = fmaf(m2qa, rcL, waccL[r]);
                    waccH[r] = fmaf(m2qa, rcH, waccH[r]);
                }
            }
#pragma unroll
            for (int r = 0; r < 4; ++r) { waccL[r] += sq; waccH[r] += sq; }
        } else {
            float sqA = 0.0f, sqB = 0.0f;
#pragma unroll 1
            for (int nt = 0; nt < 8; ++nt) {
                const int n = nt * 16 + l15;
                const float qa  = qpA[n];
                const float qb2 = qpA[128 + n];
                const float bz = bkz_lds[n];
                f32x4 cL = {bz, bz, bz, bz}, cH = {bz, bz, bz, bz};
#pragma unroll
                for (int ks = 0; ks < 4; ++ks) {
                    const bf16x8 wf = wldsv[(n << 4) + ((ks * 4 + quad) ^ l15)];
                    cL = MFMA16(aiL[ks], wf, cL);
                    cH = MFMA16(aiH[ks], wf, cH);
                }
                const float m2qa = -2.0f * qa, m2qb = -2.0f * qb2;
                sqA += qa; sqB += qb2;
#pragma unroll
                for (int r = 0; r < 4; ++r) {
                    const float rcL = RCPF(EXP2F(cL[r]) + 1.0f);
                    const float rcH = RCPF(EXP2F(cH[r]) + 1.0f);
                    waccL[r] = fmaf((quad * 4 + r      < bb) ? m2qa : m2qb, rcL, waccL[r]);
                    waccH[r] = fmaf((quad * 4 + r + 16 < bb) ? m2qa : m2qb, rcH, waccH[r]);
                }
            }
#pragma unroll
            for (int r = 0; r < 4; ++r) {
                waccL[r] += (quad * 4 + r      < bb) ? sqA : sqB;
                waccH[r] += (quad * 4 + r + 16 < bb) ? sqA : sqB;
            }
        }
        // ---- w: reduce over 16 cols within quad + padding mask ----
        float wL[4], wH[4];
#pragma unroll
        for (int r = 0; r < 4; ++r) {
            float t = waccL[r];
            t += __shfl_xor(t, 1); t += __shfl_xor(t, 2);
            t += __shfl_xor(t, 4); t += __shfl_xor(t, 8);
            wL[r] = ((mb >> (quad * 4 + r)) & 1ull) ? t : 0.0f;
            float u = waccH[r];
            u += __shfl_xor(u, 1); u += __shfl_xor(u, 2);
            u += __shfl_xor(u, 4); u += __shfl_xor(u, 8);
            wH[r] = ((mb >> (16 + quad * 4 + r)) & 1ull) ? u : 0.0f;
        }
        // ---- gather opin rows -> second A-frags (chained MFMA linearity) ----
        const int odL = __shfl(vo, l15);
        const int odH = __shfl(vo, l15 + 16);
        bf16x8 aoL[4], aoH[4];
        if (BF16) {
            const bf16x8* pL = (const bf16x8*)opb + (size_t)odL * 16 + quad;
            const bf16x8* pH = (const bf16x8*)opb + (size_t)odH * 16 + quad;
#pragma unroll
            for (int ks = 0; ks < 4; ++ks) { aoL[ks] = pL[ks * 4]; aoH[ks] = pH[ks * 4]; }
        } else {
            const float* pL = opin_table + (size_t)odL * 128 + quad * 8;
            const float* pH = opin_table + (size_t)odH * 128 + quad * 8;
#pragma unroll
            for (int ks = 0; ks < 4; ++ks) {
                aoL[ks] = pack2(*(const float4*)(pL + ks * 32), *(const float4*)(pL + ks * 32 + 4));
                aoH[ks] = pack2(*(const float4*)(pH + ks * 32), *(const float4*)(pH + ks * 32 + 4));
            }
        }
        // ---- V pass: folded tanh; one wf read feeds 4 MFMAs ----
        float m2wL[4], m2wH[4]; float wsL = 0.0f, wsH = 0.0f;
#pragma unroll
        for (int r = 0; r < 4; ++r) {
            m2wL[r] = -2.0f * wL[r]; wsL += wL[r];
            m2wH[r] = -2.0f * wH[r]; wsH += wH[r];
        }
        float* outbase = out + (size_t)uA * 128 + quad * 32 + l15;
        if (!split) {
            float s0 = 0.0f, s1 = 0.0f;
#pragma unroll 1
            for (int nt = 0; nt < 8; ++nt) {
                const int n = nt * 16 + l15;
                const float bz = bvz_lds[n];
                f32x4 cL = {bz, bz, bz, bz}, cH = {bz, bz, bz, bz};
#pragma unroll
                for (int ks = 0; ks < 4; ++ks) {
                    const bf16x8 wf = wldsv[2048 + (n << 4) + ((ks * 4 + quad) ^ l15)];
                    cL = MFMA16(aiL[ks], wf, cL);
                    cL = MFMA16(aoL[ks], wf, cL);
                    cH = MFMA16(aiH[ks], wf, cH);
                    cH = MFMA16(aoH[ks], wf, cH);
                }
                float accL = wsL, accH = wsH;
#pragma unroll
                for (int r = 0; r < 4; ++r) {
                    const float rcL = RCPF(EXP2F(cL[r]) + 1.0f);
                    const float rcH = RCPF(EXP2F(cH[r]) + 1.0f);
                    accL = fmaf(m2wL[r], rcL, accL);
                    accH = fmaf(m2wH[r], rcH, accH);
                }
                float acc = accL + accH;
                acc += __shfl_xor(acc, 16);
                acc += __shfl_xor(acc, 32);
                const bool mine = (quad == (nt >> 1));
                s0 += (mine && !(nt & 1)) ? acc : 0.0f;
                s1 += (mine &&  (nt & 1)) ? acc : 0.0f;
            }
            atomicAdd(outbase, s0);
            atomicAdd(outbase + 16, s1);
        } else {
            float m2wAL[4], m2wAH[4]; float wsAL = 0.0f, wsAH = 0.0f;
#pragma unroll
            for (int r = 0; r < 4; ++r) {
                const bool sL = (quad * 4 + r)      < bb;
                const bool sH = (quad * 4 + r + 16) < bb;
                m2wAL[r] = sL ? m2wL[r] : 0.0f; wsAL += sL ? wL[r] : 0.0f;
                m2wAH[r] = sH ? m2wH[r] : 0.0f; wsAH += sH ? wH[r] : 0.0f;
            }
            float sA0 = 0.0f, sA1 = 0.0f, sB0 = 0.0f, sB1 = 0.0f;
#pragma unroll 1
            for (int nt = 0; nt < 8; ++nt) {
                const int n = nt * 16 + l15;
                const float bz = bvz_lds[n];
                f32x4 cL = {bz, bz, bz, bz}, cH = {bz, bz, bz, bz};
#pragma unroll
                for (int ks = 0; ks < 4; ++ks) {
                    const bf16x8 wf = wldsv[2048 + (n << 4) + ((ks * 4 + quad) ^ l15)];
                    cL = MFMA16(aiL[ks], wf, cL);
                    cL = MFMA16(aoL[ks], wf, cL);
                    cH = MFMA16(aiH[ks], wf, cH);
                    cH = MFMA16(aoH[ks], wf, cH);
                }
                float accTL = wsL, accTH = wsH, accAL = wsAL, accAH = wsAH;
#pragma unroll
                for (int r = 0; r < 4; ++r) {
                    const float rcL = RCPF(EXP2F(cL[r]) + 1.0f);
                    const float rcH = RCPF(EXP2F(cH[r]) + 1.0f);
                    accTL = fmaf(m2wL[r],  rcL, accTL);
                    accAL = fmaf(m2wAL[r], rcL, accAL);
                    accTH = fmaf(m2wH[r],  rcH, accTH);
                    accAH = fmaf(m2wAH[r], rcH, accAH);
                }
                float accT = accTL + accTH;
                float accA = accAL + accAH;
                accT += __shfl_xor(accT, 16); accT += __shfl_xor(accT, 32);
                accA += __shfl_xor(accA, 16); accA += __shfl_xor(accA, 32);
                const float accB = accT - accA;
                const bool mine = (quad == (nt >> 1));
                const bool lo = !(nt & 1);
                sA0 += (mine && lo)  ? accA : 0.0f;
                sA1 += (mine && !lo) ? accA : 0.0f;
                sB0 += (mine && lo)  ? accB : 0.0f;
                sB1 += (mine && !lo) ? accB : 0.0f;
            }
            atomicAdd(outbase, sA0);
            atomicAdd(outbase + 16, sA1);
            atomicAdd(outbase + 128, sB0);        // user uA+1
            atomicAdd(outbase + 144, sB1);
        }
    }
}

extern "C" void kernel_launch(void* const* d_in, const int* in_sizes, int n_in,
                              void* d_out, int out_size, void* d_ws, size_t ws_size,
                              hipStream_t stream) {
    const float* item_table = (const float*)d_in[0];
    const float* opin_table = (const float*)d_in[1];
    const float* user_emb   = (const float*)d_in[2];
    const float* attr       = (const float*)d_in[3];
    const float* Wq = (const float*)d_in[4];
    const float* bq = (const float*)d_in[5];
    const float* Wk = (const float*)d_in[6];
    const float* bk = (const float*)d_in[7];
    const float* Wv = (const float*)d_in[8];
    const float* bv = (const float*)d_in[9];
    const int* item_seqs = (const int*)d_in[10];
    const int* opin_seqs = (const int*)d_in[11];
    float* out = (float*)d_out;

    const int U = in_sizes[2] / 128;        // 10000
    const int L = in_sizes[10] / U;         // 50
    const int n_item = in_sizes[0] / 128;   // 50000
    const int n_opi  = in_sizes[1] / 128;   // 5000

    // ---- ws layout ----
    char* w = (char*)d_ws;
    float* q_ws   = (float*)w;               w += (size_t)U * 128 * 4;
    float* bkz_ws = (float*)w;               w += 512;
    float* bvz_ws = (float*)w;               w += 512;
    short* wf_ws  = (short*)w;               w += 4096 * 16;
    short* itb    = (short*)w;               w += (size_t)n_item * 128 * 2;
    short* opb    = (short*)w;               w += (size_t)n_opi * 128 * 2;
    const size_t need = (size_t)(w - (char*)d_ws);
    const int use_bf16 = (ws_size >= need) ? 1 : 0;

    const int qb = (U + 63) / 64;
    const int castb = use_bf16 ? (((n_item + n_opi) * 16 + 255) / 256) : 0;
    const int prep_grid = qb + 49 + castb;
    finerec_prep<<<prep_grid, 256, 0, stream>>>(
        user_emb, attr, Wq, bq, Wk, bk, Wv, bv, item_table, opin_table,
        q_ws, bkz_ws, bvz_ws, wf_ws, itb, opb, out, U, n_item, n_opi, qb);

    // 512 blocks x 512 threads, grid-stride over 32-row jobs.
    if (use_bf16) {
        if (L == 50)
            finerec_main<1, 50><<<512, 512, 0, stream>>>(
                item_table, opin_table, item_seqs, opin_seqs,
                q_ws, bkz_ws, bvz_ws, wf_ws, itb, opb, out, U, L);
        else
            finerec_main<1, 0><<<512, 512, 0, stream>>>(
                item_table, opin_table, item_seqs, opin_seqs,
                q_ws, bkz_ws, bvz_ws, wf_ws, itb, opb, out, U, L);
    } else {
        if (L == 50)
            finerec_main<0, 50><<<512, 512, 0, stream>>>(
                item_table, opin_table, item_seqs, opin_seqs,
                q_ws, bkz_ws, bvz_ws, wf_ws, itb, opb, out, U, L);
        else
            finerec_main<0, 0><<<512, 512, 0, stream>>>(
                item_table, opin_table, item_seqs, opin_seqs,
                q_ws, bkz_ws, bvz_ws, wf_ws, itb, opb, out, U, L);
    }
}

// Round 8
// 184.341 us; speedup vs baseline: 1.1188x; 1.0113x over previous
//
#include <hip/hip_runtime.h>
#include <hip/hip_bf16.h>
#include <stdint.h>

typedef __attribute__((ext_vector_type(8))) short bf16x8;
typedef __attribute__((ext_vector_type(4))) float f32x4;

#define S_2LOG2E 2.8853900817779268f   // 2*log2(e): tanh(x)=1-2/(2^(x*S)+1)

#if __has_builtin(__builtin_amdgcn_exp2f)
#define EXP2F(x) __builtin_amdgcn_exp2f(x)
#else
#define EXP2F(x) __expf((x) * 0.6931471805599453f)
#endif
#if __has_builtin(__builtin_amdgcn_rcpf)
#define RCPF(x) __builtin_amdgcn_rcpf(x)
#else
#define RCPF(x) (1.0f / (x))
#endif

// tanh given pre-scaled argument z = S*(x) : returns tanh(x)
__device__ __forceinline__ float tanh_z(float z) {
    float e = EXP2F(z);
    float r = RCPF(e + 1.0f);
    return fmaf(-2.0f, r, 1.0f);
}
__device__ __forceinline__ float tanh_fast(float x) {   // prep only
    float e = __expf(2.0f * x);
    return 1.0f - 2.0f / (e + 1.0f);
}

// ---- bf16 pack via native v_cvt_pk_bf16_f32 (RNE) ----
__device__ __forceinline__ bf16x8 pack2(float4 a, float4 b) {
    union { bf16x8 v; __hip_bfloat162 h[4]; } r;
    r.h[0] = __float22bfloat162_rn(make_float2(a.x, a.y));
    r.h[1] = __float22bfloat162_rn(make_float2(a.z, a.w));
    r.h[2] = __float22bfloat162_rn(make_float2(b.x, b.y));
    r.h[3] = __float22bfloat162_rn(make_float2(b.z, b.w));
    return r.v;
}
__device__ __forceinline__ float4 scl4(float4 a) {      // fold S into W at cast time
    a.x *= S_2LOG2E; a.y *= S_2LOG2E; a.z *= S_2LOG2E; a.w *= S_2LOG2E;
    return a;
}
#define MFMA16(a, b, c) __builtin_amdgcn_mfma_f32_16x16x32_bf16((a), (b), (c), 0, 0, 0)

// =========================================================================
// Kernel 1 (prep): q, scaled biases, scaled W frags, out-zero, bf16 table
// cast (1 chunk/thread). Unchanged.
// =========================================================================
__global__ void finerec_prep(
    const float* __restrict__ user_emb, const float* __restrict__ attr,
    const float* __restrict__ Wq, const float* __restrict__ bq,
    const float* __restrict__ Wk, const float* __restrict__ bk,
    const float* __restrict__ Wv, const float* __restrict__ bv,
    const float* __restrict__ item_table, const float* __restrict__ opin_table,
    float* __restrict__ q_ws, float* __restrict__ bkz_ws, float* __restrict__ bvz_ws,
    short* __restrict__ wf_ws, short* __restrict__ itb, short* __restrict__ opb,
    float* __restrict__ out, int U, int n_item, int n_opi, int qb)
{
    const int bx = blockIdx.x, tid = threadIdx.x;
    if (bx >= qb + 49) {                     // ---- table cast to bf16 chunks ----
        const int castb = gridDim.x - qb - 49;
        const int gid = (bx - qb - 49) * 256 + tid;
        const int stride = castb * 256;
        const int tci = n_item * 16, tc = (n_item + n_opi) * 16;
        for (int c = gid; c < tc; c += stride) {
            if (c < tci) {
                const float* src = item_table + (size_t)c * 8;
                ((bf16x8*)itb)[c] = pack2(*(const float4*)src, *(const float4*)(src + 4));
            } else {
                const float* src = opin_table + (size_t)(c - tci) * 8;
                ((bf16x8*)opb)[c - tci] = pack2(*(const float4*)src, *(const float4*)(src + 4));
            }
        }
        return;
    }
    if (bx >= qb + 9) {                      // ---- zero the atomic output ----
        const int gid = (bx - qb - 9) * 256 + tid;
        float4 z = {0.0f, 0.0f, 0.0f, 0.0f};
        for (int i = gid; i < U * 32; i += 40 * 256) ((float4*)out)[i] = z;
        return;
    }
    if (bx >= qb + 1) {                      // ---- weight cast (pre-scaled by S) ----
        const int bi = bx - qb - 1;
#pragma unroll
        for (int t = 0; t < 2; ++t) {
            const int g = bi * 512 + t * 256 + tid;           // 0..4095
            const int mat = g >> 11, gg = g & 2047, r = gg >> 4, c = gg & 15;
            const float* src = (mat ? Wv : Wk) + r * 128 + c * 8;
            ((bf16x8*)wf_ws)[(mat << 11) + (r << 4) + (c ^ (r & 15))] =
                pack2(scl4(*(const float4*)src), scl4(*(const float4*)(src + 4)));
        }
        return;
    }
    if (bx == qb) {                          // ---- pre-scaled biases ----
        if (tid < 128) {
            const float* wr = Wk + tid * 128;
            float s = bk[tid];
            for (int k = 0; k < 128; k += 4) {
                float4 w4 = *(const float4*)(wr + k);
                float4 a4 = *(const float4*)(attr + k);
                s += w4.x * a4.x + w4.y * a4.y + w4.z * a4.z + w4.w * a4.w;
            }
            bkz_ws[tid] = s * S_2LOG2E;
        } else if (tid < 256) {
            bvz_ws[tid - 128] = bv[tid - 128] * S_2LOG2E;
        }
        return;
    }
    // ---- q: 64 users per block (16 per wave) ----
    const int wv = tid >> 6, lane = tid & 63;
    const int l15 = lane & 15, quad = lane >> 4;
    const int u0 = (bx * 4 + wv) * 16;
    int ur = u0 + l15; if (ur >= U) ur = U - 1;
    const float* up = user_emb + (size_t)ur * 128 + quad * 8;
    bf16x8 af[4];
#pragma unroll
    for (int ks = 0; ks < 4; ++ks)
        af[ks] = pack2(*(const float4*)(up + ks * 32), *(const float4*)(up + ks * 32 + 4));
#pragma unroll
    for (int nt = 0; nt < 8; ++nt) {
        const int n = nt * 16 + l15;
        const float* wp = Wq + n * 128 + quad * 8;
        f32x4 acc = {0, 0, 0, 0};
#pragma unroll
        for (int ks = 0; ks < 4; ++ks) {
            bf16x8 bf = pack2(*(const float4*)(wp + ks * 32), *(const float4*)(wp + ks * 32 + 4));
            acc = MFMA16(af[ks], bf, acc);
        }
        const float bqv = bq[n];
#pragma unroll
        for (int r = 0; r < 4; ++r) {
            int row = u0 + quad * 4 + r;
            if (row < U) q_ws[row * 128 + nt * 16 + l15] = tanh_fast(acc[r] + bqv);
        }
    }
}

// =========================================================================
// Kernel 2 (main): ROUND-1 VERBATIM (empirical best: 83.4us main; every
// departure regressed — VMEM-W r2, unroll+cap r4, fold+scalarize r5,
// 32-row r7) with ONE change: the OPIN GATHER IS HOISTED above the K pass.
// It depends only on vo (loaded at job top), not on K results — issuing it
// early lets the 16x256B scattered loads stay in flight under ~2000 cyc of
// K-pass compute instead of stalling the V pass (T14 issue-early). Cost:
// ao[4] live through K pass, +16 VGPR -> ~64 total = exactly the 8-wave/
// SIMD cap at 1024-thread blocks. launch_bounds(1024,4) as R1 (harmless:
// cap 64 >= natural).
// =========================================================================
template<int BF16, int LC>
__global__ __launch_bounds__(1024, 4) void finerec_main(
    const float* __restrict__ item_table, const float* __restrict__ opin_table,
    const int* __restrict__ item_seqs, const int* __restrict__ opin_seqs,
    const float* __restrict__ q_ws, const float* __restrict__ bkz_ws,
    const float* __restrict__ bvz_ws, const short* __restrict__ wf_ws,
    const short* __restrict__ itb, const short* __restrict__ opb,
    float* __restrict__ out, int U, int Lrt)
{
    __shared__ __align__(16) short wlds[32768];   // S*Wk + S*Wv frag chunks
    __shared__ float bkz_lds[128], bvz_lds[128];

    const int L = LC ? LC : Lrt;
    const int tid = threadIdx.x;
    const int wv = tid >> 6, lane = tid & 63, l15 = lane & 15, quad = lane >> 4;

    const bf16x8* wsrc = (const bf16x8*)wf_ws;
    bf16x8* wldsv = (bf16x8*)wlds;
#pragma unroll
    for (int i = 0; i < 4; ++i)
        wldsv[i * 1024 + tid] = wsrc[i * 1024 + tid];
    if (tid < 128)      bkz_lds[tid]       = bkz_ws[tid];
    else if (tid < 256) bvz_lds[tid - 128] = bvz_ws[tid - 128];
    __syncthreads();   // the ONLY block barrier

    const int UL = U * L;
    const int njobs = (UL + 15) >> 4;
    const int nwaves = gridDim.x * 16;

#pragma unroll 1
    for (int job = blockIdx.x * 16 + wv; job < njobs; job += nwaves) {
        const int g0 = job << 4;                 // first flattened row
        const int uA = g0 / L;                   // wave-uniform -> SALU/magic-mul
        const int bb = L - (g0 - uA * L);        // rows of uA in this job (may be >16)
        const bool split = (bb < 16) && (uA + 1 < U);

        int vi = 0, vo = 0;
        if (lane < 16 && g0 + lane < UL) {
            vi = item_seqs[g0 + lane];
            vo = opin_seqs[g0 + lane];
        }
        const unsigned long long mb = __ballot(vi > 0);

        // ---- gather item rows -> A-frags ----
        const int idx = __shfl(vi, l15);
        bf16x8 ai[4];
        if (BF16) {
            const bf16x8* pb = (const bf16x8*)itb + (size_t)idx * 16 + quad;
#pragma unroll
            for (int ks = 0; ks < 4; ++ks) ai[ks] = pb[ks * 4];
        } else {
            const float* p = item_table + (size_t)idx * 128 + quad * 8;
#pragma unroll
            for (int ks = 0; ks < 4; ++ks)
                ai[ks] = pack2(*(const float4*)(p + ks * 32), *(const float4*)(p + ks * 32 + 4));
        }
        // ---- HOISTED: gather opin rows NOW; loads fly under the K pass ----
        const int od = __shfl(vo, l15);
        bf16x8 ao[4];
        if (BF16) {
            const bf16x8* pb = (const bf16x8*)opb + (size_t)od * 16 + quad;
#pragma unroll
            for (int ks = 0; ks < 4; ++ks) ao[ks] = pb[ks * 4];
        } else {
            const float* p = opin_table + (size_t)od * 128 + quad * 8;
#pragma unroll
            for (int ks = 0; ks < 4; ++ks)
                ao[ks] = pack2(*(const float4*)(p + ks * 32), *(const float4*)(p + ks * 32 + 4));
        }

        const float* qpA = q_ws + (size_t)uA * 128;
        float w[4] = {0, 0, 0, 0};

        // ---- K pass: c init = pre-scaled bias, W pre-scaled -> tanh_z(c) ----
        if (!split) {
#pragma unroll 1
            for (int nt = 0; nt < 8; ++nt) {
                const int n = nt * 16 + l15;
                const float qa = qpA[n];
                const float bz = bkz_lds[n];
                f32x4 c = {bz, bz, bz, bz};
#pragma unroll
                for (int ks = 0; ks < 4; ++ks)
                    c = MFMA16(ai[ks], wldsv[(n << 4) + ((ks * 4 + quad) ^ l15)], c);
#pragma unroll
                for (int r = 0; r < 4; ++r)
                    w[r] = fmaf(qa, tanh_z(c[r]), w[r]);
            }
        } else {
            const float* qpB = qpA + 128;
#pragma unroll 1
            for (int nt = 0; nt < 8; ++nt) {
                const int n = nt * 16 + l15;
                const float qa = qpA[n];
                const float qb2 = qpB[n];
                const float bz = bkz_lds[n];
                f32x4 c = {bz, bz, bz, bz};
#pragma unroll
                for (int ks = 0; ks < 4; ++ks)
                    c = MFMA16(ai[ks], wldsv[(n << 4) + ((ks * 4 + quad) ^ l15)], c);
#pragma unroll
                for (int r = 0; r < 4; ++r) {
                    const float qv = (quad * 4 + r < bb) ? qa : qb2;
                    w[r] = fmaf(qv, tanh_z(c[r]), w[r]);
                }
            }
        }
        // ---- w: reduce over 16 cols within quad + padding mask ----
#pragma unroll
        for (int r = 0; r < 4; ++r) {
            float t = w[r];
            t += __shfl_xor(t, 1); t += __shfl_xor(t, 2);
            t += __shfl_xor(t, 4); t += __shfl_xor(t, 8);
            w[r] = ((mb >> (quad * 4 + r)) & 1ull) ? t : 0.0f;
        }
        // ---- V pass: c = (item + opin) @ S*Wv via chained MFMAs ----
        float* op = out + (size_t)uA * 128 + quad * 32 + l15;
        if (!split) {
            float s0 = 0.0f, s1 = 0.0f;
#pragma unroll 1
            for (int nt = 0; nt < 8; ++nt) {
                const int n = nt * 16 + l15;
                const float bz = bvz_lds[n];
                f32x4 c = {bz, bz, bz, bz};
#pragma unroll
                for (int ks = 0; ks < 4; ++ks) {
                    const bf16x8 wf = wldsv[2048 + (n << 4) + ((ks * 4 + quad) ^ l15)];
                    c = MFMA16(ai[ks], wf, c);
                    c = MFMA16(ao[ks], wf, c);
                }
                float acc = 0.0f;
#pragma unroll
                for (int r = 0; r < 4; ++r)
                    acc = fmaf(w[r], tanh_z(c[r]), acc);
                acc += __shfl_xor(acc, 16);
                acc += __shfl_xor(acc, 32);
                const bool mine = (quad == (nt >> 1));
                s0 += (mine && !(nt & 1)) ? acc : 0.0f;
                s1 += (mine &&  (nt & 1)) ? acc : 0.0f;
            }
            atomicAdd(op, s0);
            atomicAdd(op + 16, s1);
        } else {
            float sA0 = 0.0f, sA1 = 0.0f, sB0 = 0.0f, sB1 = 0.0f;
#pragma unroll 1
            for (int nt = 0; nt < 8; ++nt) {
                const int n = nt * 16 + l15;
                const float bz = bvz_lds[n];
                f32x4 c = {bz, bz, bz, bz};
#pragma unroll
                for (int ks = 0; ks < 4; ++ks) {
                    const bf16x8 wf = wldsv[2048 + (n << 4) + ((ks * 4 + quad) ^ l15)];
                    c = MFMA16(ai[ks], wf, c);
                    c = MFMA16(ao[ks], wf, c);
                }
                float accT = 0.0f, accA = 0.0f;
#pragma unroll
                for (int r = 0; r < 4; ++r) {
                    const float t = w[r] * tanh_z(c[r]);
                    accT += t;
                    accA += (quad * 4 + r < bb) ? t : 0.0f;
                }
                accT += __shfl_xor(accT, 16); accT += __shfl_xor(accT, 32);
                accA += __shfl_xor(accA, 16); accA += __shfl_xor(accA, 32);
                const float accB = accT - accA;
                const bool mine = (quad == (nt >> 1));
                const bool lo = !(nt & 1);
                sA0 += (mine && lo)  ? accA : 0.0f;
                sA1 += (mine && !lo) ? accA : 0.0f;
                sB0 += (mine && lo)  ? accB : 0.0f;
                sB1 += (mine && !lo) ? accB : 0.0f;
            }
            atomicAdd(op, sA0);
            atomicAdd(op + 16, sA1);
            atomicAdd(op + 128, sB0);        // user uA+1
            atomicAdd(op + 144, sB1);
        }
    }
}

extern "C" void kernel_launch(void* const* d_in, const int* in_sizes, int n_in,
                              void* d_out, int out_size, void* d_ws, size_t ws_size,
                              hipStream_t stream) {
    const float* item_table = (const float*)d_in[0];
    const float* opin_table = (const float*)d_in[1];
    const float* user_emb   = (const float*)d_in[2];
    const float* attr       = (const float*)d_in[3];
    const float* Wq = (const float*)d_in[4];
    const float* bq = (const float*)d_in[5];
    const float* Wk = (const float*)d_in[6];
    const float* bk = (const float*)d_in[7];
    const float* Wv = (const float*)d_in[8];
    const float* bv = (const float*)d_in[9];
    const int* item_seqs = (const int*)d_in[10];
    const int* opin_seqs = (const int*)d_in[11];
    float* out = (float*)d_out;

    const int U = in_sizes[2] / 128;        // 10000
    const int L = in_sizes[10] / U;         // 50
    const int n_item = in_sizes[0] / 128;   // 50000
    const int n_opi  = in_sizes[1] / 128;   // 5000

    // ---- ws layout ----
    char* w = (char*)d_ws;
    float* q_ws   = (float*)w;               w += (size_t)U * 128 * 4;
    float* bkz_ws = (float*)w;               w += 512;
    float* bvz_ws = (float*)w;               w += 512;
    short* wf_ws  = (short*)w;               w += 4096 * 16;
    short* itb    = (short*)w;               w += (size_t)n_item * 128 * 2;
    short* opb    = (short*)w;               w += (size_t)n_opi * 128 * 2;
    const size_t need = (size_t)(w - (char*)d_ws);
    const int use_bf16 = (ws_size >= need) ? 1 : 0;

    const int qb = (U + 63) / 64;
    const int castb = use_bf16 ? (((n_item + n_opi) * 16 + 255) / 256) : 0;
    const int prep_grid = qb + 49 + castb;
    finerec_prep<<<prep_grid, 256, 0, stream>>>(
        user_emb, attr, Wq, bq, Wk, bk, Wv, bv, item_table, opin_table,
        q_ws, bkz_ws, bvz_ws, wf_ws, itb, opb, out, U, n_item, n_opi, qb);

    if (use_bf16) {
        if (L == 50)
            finerec_main<1, 50><<<512, 1024, 0, stream>>>(
                item_table, opin_table, item_seqs, opin_seqs,
                q_ws, bkz_ws, bvz_ws, wf_ws, itb, opb, out, U, L);
        else
            finerec_main<1, 0><<<512, 1024, 0, stream>>>(
                item_table, opin_table, item_seqs, opin_seqs,
                q_ws, bkz_ws, bvz_ws, wf_ws, itb, opb, out, U, L);
    } else {
        if (L == 50)
            finerec_main<0, 50><<<512, 1024, 0, stream>>>(
                item_table, opin_table, item_seqs, opin_seqs,
                q_ws, bkz_ws, bvz_ws, wf_ws, itb, opb, out, U, L);
        else
            finerec_main<0, 0><<<512, 1024, 0, stream>>>(
                item_table, opin_table, item_seqs, opin_seqs,
                q_ws, bkz_ws, bvz_ws, wf_ws, itb, opb, out, U, L);
    }
}

// Round 9
// 179.633 us; speedup vs baseline: 1.1482x; 1.0262x over previous
//
#include <hip/hip_runtime.h>
#include <hip/hip_bf16.h>
#include <stdint.h>

typedef __attribute__((ext_vector_type(8))) short bf16x8;
typedef __attribute__((ext_vector_type(4))) float f32x4;

#define S_2LOG2E 2.8853900817779268f   // 2*log2(e): tanh(x)=1-2/(2^(x*S)+1)

#if __has_builtin(__builtin_amdgcn_exp2f)
#define EXP2F(x) __builtin_amdgcn_exp2f(x)
#else
#define EXP2F(x) __expf((x) * 0.6931471805599453f)
#endif
#if __has_builtin(__builtin_amdgcn_rcpf)
#define RCPF(x) __builtin_amdgcn_rcpf(x)
#else
#define RCPF(x) (1.0f / (x))
#endif

// tanh given pre-scaled argument z = S*(x) : returns tanh(x)
__device__ __forceinline__ float tanh_z(float z) {
    float e = EXP2F(z);
    float r = RCPF(e + 1.0f);
    return fmaf(-2.0f, r, 1.0f);
}
__device__ __forceinline__ float tanh_fast(float x) {   // prep only
    float e = __expf(2.0f * x);
    return 1.0f - 2.0f / (e + 1.0f);
}

// ---- bf16 pack via native v_cvt_pk_bf16_f32 (RNE) ----
__device__ __forceinline__ bf16x8 pack2(float4 a, float4 b) {
    union { bf16x8 v; __hip_bfloat162 h[4]; } r;
    r.h[0] = __float22bfloat162_rn(make_float2(a.x, a.y));
    r.h[1] = __float22bfloat162_rn(make_float2(a.z, a.w));
    r.h[2] = __float22bfloat162_rn(make_float2(b.x, b.y));
    r.h[3] = __float22bfloat162_rn(make_float2(b.z, b.w));
    return r.v;
}
__device__ __forceinline__ float4 scl4(float4 a) {      // fold S into W at cast time
    a.x *= S_2LOG2E; a.y *= S_2LOG2E; a.z *= S_2LOG2E; a.w *= S_2LOG2E;
    return a;
}
#define MFMA16(a, b, c) __builtin_amdgcn_mfma_f32_16x16x32_bf16((a), (b), (c), 0, 0, 0)

// =========================================================================
// Kernel 1 (prep), grid sections by blockIdx:
//  [0,qb)        q = tanh(user @ Wq^T + bq) -> q_ws
//  qb            bkz = S*(bk + Wk@attr), bvz = S*bv
//  (qb, qb+8]    S*Wk, S*Wv -> bf16 XOR-swizzled frag chunks -> wf_ws
//  (qb+8, qb+48] zero out (atomic target)
//  rest          item/opin tables -> bf16 chunks (1 chunk/thread)
// =========================================================================
__global__ void finerec_prep(
    const float* __restrict__ user_emb, const float* __restrict__ attr,
    const float* __restrict__ Wq, const float* __restrict__ bq,
    const float* __restrict__ Wk, const float* __restrict__ bk,
    const float* __restrict__ Wv, const float* __restrict__ bv,
    const float* __restrict__ item_table, const float* __restrict__ opin_table,
    float* __restrict__ q_ws, float* __restrict__ bkz_ws, float* __restrict__ bvz_ws,
    short* __restrict__ wf_ws, short* __restrict__ itb, short* __restrict__ opb,
    float* __restrict__ out, int U, int n_item, int n_opi, int qb)
{
    const int bx = blockIdx.x, tid = threadIdx.x;
    if (bx >= qb + 49) {                     // ---- table cast to bf16 chunks ----
        const int castb = gridDim.x - qb - 49;
        const int gid = (bx - qb - 49) * 256 + tid;
        const int stride = castb * 256;
        const int tci = n_item * 16, tc = (n_item + n_opi) * 16;
        for (int c = gid; c < tc; c += stride) {
            if (c < tci) {
                const float* src = item_table + (size_t)c * 8;
                ((bf16x8*)itb)[c] = pack2(*(const float4*)src, *(const float4*)(src + 4));
            } else {
                const float* src = opin_table + (size_t)(c - tci) * 8;
                ((bf16x8*)opb)[c - tci] = pack2(*(const float4*)src, *(const float4*)(src + 4));
            }
        }
        return;
    }
    if (bx >= qb + 9) {                      // ---- zero the atomic output ----
        const int gid = (bx - qb - 9) * 256 + tid;
        float4 z = {0.0f, 0.0f, 0.0f, 0.0f};
        for (int i = gid; i < U * 32; i += 40 * 256) ((float4*)out)[i] = z;
        return;
    }
    if (bx >= qb + 1) {                      // ---- weight cast (pre-scaled by S) ----
        const int bi = bx - qb - 1;
#pragma unroll
        for (int t = 0; t < 2; ++t) {
            const int g = bi * 512 + t * 256 + tid;           // 0..4095
            const int mat = g >> 11, gg = g & 2047, r = gg >> 4, c = gg & 15;
            const float* src = (mat ? Wv : Wk) + r * 128 + c * 8;
            ((bf16x8*)wf_ws)[(mat << 11) + (r << 4) + (c ^ (r & 15))] =
                pack2(scl4(*(const float4*)src), scl4(*(const float4*)(src + 4)));
        }
        return;
    }
    if (bx == qb) {                          // ---- pre-scaled biases ----
        if (tid < 128) {
            const float* wr = Wk + tid * 128;
            float s = bk[tid];
            for (int k = 0; k < 128; k += 4) {
                float4 w4 = *(const float4*)(wr + k);
                float4 a4 = *(const float4*)(attr + k);
                s += w4.x * a4.x + w4.y * a4.y + w4.z * a4.z + w4.w * a4.w;
            }
            bkz_ws[tid] = s * S_2LOG2E;
        } else if (tid < 256) {
            bvz_ws[tid - 128] = bv[tid - 128] * S_2LOG2E;
        }
        return;
    }
    // ---- q: 64 users per block (16 per wave) ----
    const int wv = tid >> 6, lane = tid & 63;
    const int l15 = lane & 15, quad = lane >> 4;
    const int u0 = (bx * 4 + wv) * 16;
    int ur = u0 + l15; if (ur >= U) ur = U - 1;
    const float* up = user_emb + (size_t)ur * 128 + quad * 8;
    bf16x8 af[4];
#pragma unroll
    for (int ks = 0; ks < 4; ++ks)
        af[ks] = pack2(*(const float4*)(up + ks * 32), *(const float4*)(up + ks * 32 + 4));
#pragma unroll
    for (int nt = 0; nt < 8; ++nt) {
        const int n = nt * 16 + l15;
        const float* wp = Wq + n * 128 + quad * 8;
        f32x4 acc = {0, 0, 0, 0};
#pragma unroll
        for (int ks = 0; ks < 4; ++ks) {
            bf16x8 bf = pack2(*(const float4*)(wp + ks * 32), *(const float4*)(wp + ks * 32 + 4));
            acc = MFMA16(af[ks], bf, acc);
        }
        const float bqv = bq[n];
#pragma unroll
        for (int r = 0; r < 4; ++r) {
            int row = u0 + quad * 4 + r;
            if (row < U) q_ws[row * 128 + nt * 16 + l15] = tanh_fast(acc[r] + bqv);
        }
    }
}

// =========================================================================
// Kernel 2 (main): THE EMPIRICAL BEST (round-1, 83.4us main). Flat 16-row
// jobs over U*L rows (no padding rows), all W-frags in LDS (XOR-swizzled),
// chained double-MFMA V pass (linearity), bias-in-accumulator-init with
// S pre-folded into W, per-nt q from L2, rolled nt loops (VGPR 48 -> 32
// waves/CU with 66.5KB LDS), atomicAdd epilogue into prep-zeroed out.
// Session A/B ledger (all departures regressed): VMEM-W +25% (r2),
// unroll+VGPR-cap spill +190% (r4), fold+scalarize +6% (r5), 32-row jobs
// +12% (r7), opin-gather hoist +6% (r8 — both gather sets outstanding
// couple in the pre-MFMA waitcnt). Do not re-apply without within-probe
// A/B capability; cross-container noise here is +/-5%.
// =========================================================================
template<int BF16, int LC>
__global__ __launch_bounds__(1024, 4) void finerec_main(
    const float* __restrict__ item_table, const float* __restrict__ opin_table,
    const int* __restrict__ item_seqs, const int* __restrict__ opin_seqs,
    const float* __restrict__ q_ws, const float* __restrict__ bkz_ws,
    const float* __restrict__ bvz_ws, const short* __restrict__ wf_ws,
    const short* __restrict__ itb, const short* __restrict__ opb,
    float* __restrict__ out, int U, int Lrt)
{
    __shared__ __align__(16) short wlds[32768];   // S*Wk + S*Wv frag chunks
    __shared__ float bkz_lds[128], bvz_lds[128];

    const int L = LC ? LC : Lrt;                  // LC=50: compile-time magic-mul division
    const int tid = threadIdx.x;
    const int wv = tid >> 6, lane = tid & 63, l15 = lane & 15, quad = lane >> 4;

    const bf16x8* wsrc = (const bf16x8*)wf_ws;
    bf16x8* wldsv = (bf16x8*)wlds;
#pragma unroll
    for (int i = 0; i < 4; ++i)
        wldsv[i * 1024 + tid] = wsrc[i * 1024 + tid];
    if (tid < 128)      bkz_lds[tid]       = bkz_ws[tid];
    else if (tid < 256) bvz_lds[tid - 128] = bvz_ws[tid - 128];
    __syncthreads();   // the ONLY block barrier

    const int UL = U * L;
    const int njobs = (UL + 15) >> 4;
    const int nwaves = gridDim.x * 16;

#pragma unroll 1
    for (int job = blockIdx.x * 16 + wv; job < njobs; job += nwaves) {
        const int g0 = job << 4;                 // first flattened row
        const int uA = g0 / L;                   // wave-uniform -> SALU
        const int bb = L - (g0 - uA * L);        // rows of uA in this job (may be >16)
        const bool split = (bb < 16) && (uA + 1 < U);

        int vi = 0, vo = 0;
        if (lane < 16 && g0 + lane < UL) {
            vi = item_seqs[g0 + lane];
            vo = opin_seqs[g0 + lane];
        }
        const unsigned long long mb = __ballot(vi > 0);

        // ---- gather item rows -> A-frags ----
        const int idx = __shfl(vi, l15);
        bf16x8 ai[4];
        if (BF16) {
            const bf16x8* pb = (const bf16x8*)itb + (size_t)idx * 16 + quad;
#pragma unroll
            for (int ks = 0; ks < 4; ++ks) ai[ks] = pb[ks * 4];
        } else {
            const float* p = item_table + (size_t)idx * 128 + quad * 8;
#pragma unroll
            for (int ks = 0; ks < 4; ++ks)
                ai[ks] = pack2(*(const float4*)(p + ks * 32), *(const float4*)(p + ks * 32 + 4));
        }

        const float* qpA = q_ws + (size_t)uA * 128;
        float w[4] = {0, 0, 0, 0};

        // ---- K pass: c init = pre-scaled bias, W pre-scaled -> tanh_z(c) ----
        if (!split) {
#pragma unroll 1
            for (int nt = 0; nt < 8; ++nt) {
                const int n = nt * 16 + l15;
                const float qa = qpA[n];
                const float bz = bkz_lds[n];
                f32x4 c = {bz, bz, bz, bz};
#pragma unroll
                for (int ks = 0; ks < 4; ++ks)
                    c = MFMA16(ai[ks], wldsv[(n << 4) + ((ks * 4 + quad) ^ l15)], c);
#pragma unroll
                for (int r = 0; r < 4; ++r)
                    w[r] = fmaf(qa, tanh_z(c[r]), w[r]);
            }
        } else {
            const float* qpB = qpA + 128;
#pragma unroll 1
            for (int nt = 0; nt < 8; ++nt) {
                const int n = nt * 16 + l15;
                const float qa = qpA[n];
                const float qb2 = qpB[n];
                const float bz = bkz_lds[n];
                f32x4 c = {bz, bz, bz, bz};
#pragma unroll
                for (int ks = 0; ks < 4; ++ks)
                    c = MFMA16(ai[ks], wldsv[(n << 4) + ((ks * 4 + quad) ^ l15)], c);
#pragma unroll
                for (int r = 0; r < 4; ++r) {
                    const float qv = (quad * 4 + r < bb) ? qa : qb2;
                    w[r] = fmaf(qv, tanh_z(c[r]), w[r]);
                }
            }
        }
        // ---- w: reduce over 16 cols within quad + padding mask ----
#pragma unroll
        for (int r = 0; r < 4; ++r) {
            float t = w[r];
            t += __shfl_xor(t, 1); t += __shfl_xor(t, 2);
            t += __shfl_xor(t, 4); t += __shfl_xor(t, 8);
            w[r] = ((mb >> (quad * 4 + r)) & 1ull) ? t : 0.0f;
        }
        // ---- gather opin rows -> second A-frags (linearity: no add/repack) ----
        const int od = __shfl(vo, l15);
        bf16x8 ao[4];
        if (BF16) {
            const bf16x8* pb = (const bf16x8*)opb + (size_t)od * 16 + quad;
#pragma unroll
            for (int ks = 0; ks < 4; ++ks) ao[ks] = pb[ks * 4];
        } else {
            const float* p = opin_table + (size_t)od * 128 + quad * 8;
#pragma unroll
            for (int ks = 0; ks < 4; ++ks)
                ao[ks] = pack2(*(const float4*)(p + ks * 32), *(const float4*)(p + ks * 32 + 4));
        }
        // ---- V pass: c = (item + opin) @ S*Wv via chained MFMAs ----
        float* op = out + (size_t)uA * 128 + quad * 32 + l15;
        if (!split) {
            float s0 = 0.0f, s1 = 0.0f;
#pragma unroll 1
            for (int nt = 0; nt < 8; ++nt) {
                const int n = nt * 16 + l15;
                const float bz = bvz_lds[n];
                f32x4 c = {bz, bz, bz, bz};
#pragma unroll
                for (int ks = 0; ks < 4; ++ks) {
                    const bf16x8 wf = wldsv[2048 + (n << 4) + ((ks * 4 + quad) ^ l15)];
                    c = MFMA16(ai[ks], wf, c);
                    c = MFMA16(ao[ks], wf, c);
                }
                float acc = 0.0f;
#pragma unroll
                for (int r = 0; r < 4; ++r)
                    acc = fmaf(w[r], tanh_z(c[r]), acc);
                acc += __shfl_xor(acc, 16);
                acc += __shfl_xor(acc, 32);
                const bool mine = (quad == (nt >> 1));
                s0 += (mine && !(nt & 1)) ? acc : 0.0f;
                s1 += (mine &&  (nt & 1)) ? acc : 0.0f;
            }
            atomicAdd(op, s0);
            atomicAdd(op + 16, s1);
        } else {
            float sA0 = 0.0f, sA1 = 0.0f, sB0 = 0.0f, sB1 = 0.0f;
#pragma unroll 1
            for (int nt = 0; nt < 8; ++nt) {
                const int n = nt * 16 + l15;
                const float bz = bvz_lds[n];
                f32x4 c = {bz, bz, bz, bz};
#pragma unroll
                for (int ks = 0; ks < 4; ++ks) {
                    const bf16x8 wf = wldsv[2048 + (n << 4) + ((ks * 4 + quad) ^ l15)];
                    c = MFMA16(ai[ks], wf, c);
                    c = MFMA16(ao[ks], wf, c);
                }
                float accT = 0.0f, accA = 0.0f;
#pragma unroll
                for (int r = 0; r < 4; ++r) {
                    const float t = w[r] * tanh_z(c[r]);
                    accT += t;
                    accA += (quad * 4 + r < bb) ? t : 0.0f;
                }
                accT += __shfl_xor(accT, 16); accT += __shfl_xor(accT, 32);
                accA += __shfl_xor(accA, 16); accA += __shfl_xor(accA, 32);
                const float accB = accT - accA;
                const bool mine = (quad == (nt >> 1));
                const bool lo = !(nt & 1);
                sA0 += (mine && lo)  ? accA : 0.0f;
                sA1 += (mine && !lo) ? accA : 0.0f;
                sB0 += (mine && lo)  ? accB : 0.0f;
                sB1 += (mine && !lo) ? accB : 0.0f;
            }
            atomicAdd(op, sA0);
            atomicAdd(op + 16, sA1);
            atomicAdd(op + 128, sB0);        // user uA+1
            atomicAdd(op + 144, sB1);
        }
    }
}

extern "C" void kernel_launch(void* const* d_in, const int* in_sizes, int n_in,
                              void* d_out, int out_size, void* d_ws, size_t ws_size,
                              hipStream_t stream) {
    const float* item_table = (const float*)d_in[0];
    const float* opin_table = (const float*)d_in[1];
    const float* user_emb   = (const float*)d_in[2];
    const float* attr       = (const float*)d_in[3];
    const float* Wq = (const float*)d_in[4];
    const float* bq = (const float*)d_in[5];
    const float* Wk = (const float*)d_in[6];
    const float* bk = (const float*)d_in[7];
    const float* Wv = (const float*)d_in[8];
    const float* bv = (const float*)d_in[9];
    const int* item_seqs = (const int*)d_in[10];
    const int* opin_seqs = (const int*)d_in[11];
    float* out = (float*)d_out;

    const int U = in_sizes[2] / 128;        // 10000
    const int L = in_sizes[10] / U;         // 50
    const int n_item = in_sizes[0] / 128;   // 50000
    const int n_opi  = in_sizes[1] / 128;   // 5000

    // ---- ws layout ----
    char* w = (char*)d_ws;
    float* q_ws   = (float*)w;               w += (size_t)U * 128 * 4;
    float* bkz_ws = (float*)w;               w += 512;
    float* bvz_ws = (float*)w;               w += 512;
    short* wf_ws  = (short*)w;               w += 4096 * 16;
    short* itb    = (short*)w;               w += (size_t)n_item * 128 * 2;
    short* opb    = (short*)w;               w += (size_t)n_opi * 128 * 2;
    const size_t need = (size_t)(w - (char*)d_ws);
    const int use_bf16 = (ws_size >= need) ? 1 : 0;

    const int qb = (U + 63) / 64;
    // table cast: ~1 chunk/thread so prep is BW-bound, not latency-bound
    const int castb = use_bf16 ? (((n_item + n_opi) * 16 + 255) / 256) : 0;
    const int prep_grid = qb + 49 + castb;
    finerec_prep<<<prep_grid, 256, 0, stream>>>(
        user_emb, attr, Wq, bq, Wk, bk, Wv, bv, item_table, opin_table,
        q_ws, bkz_ws, bvz_ws, wf_ws, itb, opb, out, U, n_item, n_opi, qb);

    if (use_bf16) {
        if (L == 50)
            finerec_main<1, 50><<<512, 1024, 0, stream>>>(
                item_table, opin_table, item_seqs, opin_seqs,
                q_ws, bkz_ws, bvz_ws, wf_ws, itb, opb, out, U, L);
        else
            finerec_main<1, 0><<<512, 1024, 0, stream>>>(
                item_table, opin_table, item_seqs, opin_seqs,
                q_ws, bkz_ws, bvz_ws, wf_ws, itb, opb, out, U, L);
    } else {
        if (L == 50)
            finerec_main<0, 50><<<512, 1024, 0, stream>>>(
                item_table, opin_table, item_seqs, opin_seqs,
                q_ws, bkz_ws, bvz_ws, wf_ws, itb, opb, out, U, L);
        else
            finerec_main<0, 0><<<512, 1024, 0, stream>>>(
                item_table, opin_table, item_seqs, opin_seqs,
                q_ws, bkz_ws, bvz_ws, wf_ws, itb, opb, out, U, L);
    }
}